// Round 6
// baseline (1919.380 us; speedup 1.0000x reference)
//
#include <hip/hip_runtime.h>
#include <math.h>

#define BB 1024
#define TT 512
#define FF 32
#define HH 64
#define GG 256   // 4H
#define TC 64
#define NCHUNK (TT/TC)   // 8
#define EPSBN 1e-3f

// ---------------- fold1: per-layer BN vectors + attention vector ----------------
__global__ void fold1_kernel(const float* __restrict__ gamma, const float* __restrict__ beta,
                             const float* __restrict__ mean, const float* __restrict__ var,
                             const float* __restrict__ attw, const float* __restrict__ attv,
                             float* __restrict__ s_out, float* __restrict__ ab_out,
                             float* __restrict__ wv_out) {
    int d = threadIdx.x; // 64 threads
    float s = gamma[d] * rsqrtf(var[d] + EPSBN);
    float ab = beta[d] - mean[d] * s;
    float wvr = 0.f;
    for (int e = 0; e < HH; ++e) wvr += attw[d * HH + e] * attv[e];
    s_out[d] = s;
    ab_out[d] = ab;
    wv_out[d] = s * wvr;
}

// ---------------- fold2: fold previous layer's BN into next W, b ----------------
__global__ void fold2_kernel(const float* __restrict__ W, const float* __restrict__ b,
                             const float* __restrict__ s_prev, const float* __restrict__ ab_prev,
                             float* __restrict__ Wp, float* __restrict__ bp) {
    int g = threadIdx.x; // 256 threads
    float bacc = b[g];
    for (int d = 0; d < HH; ++d) {
        float w = W[d * GG + g];
        bacc += ab_prev[d] * w;
        Wp[d * GG + g] = s_prev[d] * w;
    }
    bp[g] = bacc;
}

// ---------------- init per-call state ----------------
__global__ void init_kernel(float* st_h, float* st_c, float* st_acc, float* st_m, float* st_d) {
    int i = blockIdx.x * blockDim.x + threadIdx.x;
    int n = 3 * BB * HH;
    if (i < n) { st_h[i] = 0.f; st_c[i] = 0.f; st_acc[i] = 0.f; }
    if (i < 3 * BB) { st_m[i] = -3.0e38f; st_d[i] = 0.f; }
}

// ---------------- fused recurrent kernel ----------------
// Block = 4 waves = 1 batch row of 1 layer-chunk. Wave w = gate w; lane j = unit j.
// Weights (wx[K], u[64]) pinned into VGPRs via empty inline-asm "+v" (the compiler
// otherwise rematerializes the loads every timestep -- r5 showed VGPR_Count=84).
// One barrier per timestep; attention hoisted to a per-chunk flash epilogue.
struct RecFArgs {
    const float* xin[3]; long sB[3]; int K[3];
    const float* W[3]; const float* U[3]; const float* bias[3];
    float* Hout[3];              // nullptr -> skip
    float* st_h[3]; float* st_c[3]; float* st_acc[3];
    float* st_m[3]; float* st_d[3];
    const float* wv[3]; const float* abv[3]; const float* sbn[3];
    float* a_out[3];
    int last[3];
};

template<int K>
__device__ __forceinline__ void rec_seg(const RecFArgs& A, int seg, int b, int tid,
                                        float* xs, float* Hl, float* zsf,
                                        float* hwf, float* wv_lds, float* score_lds) {
    const int w = tid >> 6, j = tid & 63;
    const int col = (w << 6) + j;

    const float* Wp = A.W[seg];
    const float* Up = A.U[seg];
    float wx[K], u[64];
#pragma unroll
    for (int k = 0; k < K; ++k) wx[k] = Wp[k * GG + col];
#pragma unroll
    for (int k = 0; k < 64; ++k) u[k] = Up[k * GG + col];
    // Pin weights in VGPRs: opaque to the compiler -> cannot re-load from memory.
#pragma unroll
    for (int k = 0; k < K; ++k) asm volatile("" : "+v"(wx[k]));
#pragma unroll
    for (int k = 0; k < 64; ++k) asm volatile("" : "+v"(u[k]));
    const float bg = A.bias[seg][col];

    // stage x chunk (contiguous TC*K floats per batch row)
    const float4* xb4 = reinterpret_cast<const float4*>(A.xin[seg] + (long)b * A.sB[seg]);
    constexpr int NF4 = TC * K / 4;
    for (int i = tid; i < NF4; i += 256)
        reinterpret_cast<float4*>(xs)[i] = xb4[i];
    if (tid < 64) wv_lds[tid] = A.wv[seg][tid];

    const int gi = (b << 6) + j;
    float c = A.st_c[seg][gi];
    float h = A.st_h[seg][gi];
    float accv = 0.f, m_b = 0.f, d_b = 0.f;
    if (w == 0) { accv = A.st_acc[seg][gi]; m_b = A.st_m[seg][b]; d_b = A.st_d[seg][b]; }
    hwf[(w << 6) + j] = h;      // per-wave private h buffer
    __syncthreads();

    float* Hob = A.Hout[seg] ? A.Hout[seg] + (size_t)b * TC * HH + j : (float*)0;

#pragma unroll 2
    for (int t = 0; t < TC; ++t) {
        const float* xr = xs + t * K;
        float a0 = bg, a1 = 0.f;
#pragma unroll
        for (int k8 = 0; k8 < K / 8; ++k8) {
            float4 xA = *reinterpret_cast<const float4*>(xr + k8 * 8);
            float4 xB = *reinterpret_cast<const float4*>(xr + k8 * 8 + 4);
            a0 = fmaf(xA.x, wx[k8*8+0], a0); a1 = fmaf(xA.y, wx[k8*8+1], a1);
            a0 = fmaf(xA.z, wx[k8*8+2], a0); a1 = fmaf(xA.w, wx[k8*8+3], a1);
            a0 = fmaf(xB.x, wx[k8*8+4], a0); a1 = fmaf(xB.y, wx[k8*8+5], a1);
            a0 = fmaf(xB.z, wx[k8*8+6], a0); a1 = fmaf(xB.w, wx[k8*8+7], a1);
        }
        const float* hp = hwf + (w << 6);
#pragma unroll
        for (int k8 = 0; k8 < 8; ++k8) {
            float4 hA = *reinterpret_cast<const float4*>(hp + k8 * 8);
            float4 hB = *reinterpret_cast<const float4*>(hp + k8 * 8 + 4);
            a0 = fmaf(hA.x, u[k8*8+0], a0); a1 = fmaf(hA.y, u[k8*8+1], a1);
            a0 = fmaf(hA.z, u[k8*8+2], a0); a1 = fmaf(hA.w, u[k8*8+3], a1);
            a0 = fmaf(hB.x, u[k8*8+4], a0); a1 = fmaf(hB.y, u[k8*8+5], a1);
            a0 = fmaf(hB.z, u[k8*8+6], a0); a1 = fmaf(hB.w, u[k8*8+7], a1);
        }
        float acc = a0 + a1;
        float z = (w == 2) ? fmaxf(acc, 0.f)
                           : __fdividef(1.f, 1.f + __expf(-acc));
        float* zp = zsf + ((t & 1) << 8);
        zp[(w << 6) + j] = z;
        __syncthreads();                         // the ONLY barrier per timestep

        float zi = zp[j], zf = zp[64 + j], zg = zp[128 + j], zo = zp[192 + j];
        c = fmaf(zf, c, zi * zg);
        h = zo * fmaxf(c, 0.f);
        hwf[(w << 6) + j] = h;                   // own-wave buffer: no barrier needed
        if (w == 3) Hl[t * 65 + j] = h;          // for attention epilogue
        if (w == 1 && Hob) Hob[t * HH] = h;      // for next layer
    }
    __syncthreads();

    // ---- per-chunk attention epilogue (flash merge) ----
    // Phase A: scores[t] = sum_j H[t][j]*wv[j]
    {
        int tq = tid >> 2, q = tid & 3;
        float part = 0.f;
#pragma unroll
        for (int i = 0; i < 16; ++i)
            part = fmaf(Hl[tq * 65 + q * 16 + i], wv_lds[q * 16 + i], part);
        part += __shfl_xor(part, 1);
        part += __shfl_xor(part, 2);
        if (q == 0) score_lds[tq] = part;
    }
    __syncthreads();
    // Phase B: chunk max + exp + denom (all waves compute identically)
    float s = score_lds[j];
    float Mc = s;
#pragma unroll
    for (int off = 1; off < 64; off <<= 1) Mc = fmaxf(Mc, __shfl_xor(Mc, off));
    float p = __expf(s - Mc);
    float Dc = p;
#pragma unroll
    for (int off = 1; off < 64; off <<= 1) Dc += __shfl_xor(Dc, off);
    // Phase C: partial weighted sum over this wave's 16 timesteps
    {
        int wu = __builtin_amdgcn_readfirstlane(w);
        float pacc = 0.f;
#pragma unroll
        for (int tt = 0; tt < 16; ++tt) {
            float ptt = __int_as_float(
                __builtin_amdgcn_readlane(__float_as_int(p), wu * 16 + tt));
            pacc = fmaf(ptt, Hl[(wu * 16 + tt) * 65 + j], pacc);
        }
        zsf[(w << 6) + j] = pacc;                // reuse zs[0] for partials
    }
    __syncthreads();
    // Phase D: merge with running state (wave 0); store states
    if (w == 2) { A.st_c[seg][gi] = c; A.st_h[seg][gi] = h; }
    if (w == 0) {
        float Ac = zsf[j] + zsf[64 + j] + zsf[128 + j] + zsf[192 + j];
        float mnew = fmaxf(m_b, Mc);
        float corr = __expf(m_b - mnew);
        float pc = __expf(Mc - mnew);
        d_b = d_b * corr + Dc * pc;
        accv = fmaf(accv, corr, Ac * pc);
        m_b = mnew;
        A.st_acc[seg][gi] = accv;
        if (j == 0) { A.st_m[seg][b] = m_b; A.st_d[seg][b] = d_b; }
        if (A.last[seg])
            A.a_out[seg][gi] = A.sbn[seg][j] * __fdividef(accv, d_b) + A.abv[seg][j];
    }
}

__global__ __launch_bounds__(256, 2) void rec_fused(RecFArgs A) {
    __shared__ float xs[TC * 64];        // 16 KB
    __shared__ float Hl[TC * 65];        // 16.6 KB (padded, bank-conflict-free)
    __shared__ float zsf[2 * 4 * 64];    // 2 KB (parity double-buffered gates)
    __shared__ float hwf[4 * 64];        // 1 KB (per-wave h broadcast)
    __shared__ float wv_lds[64];
    __shared__ float score_lds[64];
    int seg = blockIdx.x >> 10;
    int b   = blockIdx.x & 1023;
    if (A.K[seg] == 32) rec_seg<32>(A, seg, b, threadIdx.x, xs, Hl, zsf, hwf, wv_lds, score_lds);
    else                rec_seg<64>(A, seg, b, threadIdx.x, xs, Hl, zsf, hwf, wv_lds, score_lds);
}

// ---------------- final: out[b] = db + sum_{l,j} a[l][b][j]*dw[l*64+j] ----------------
__global__ void final_kernel(const float* __restrict__ a, const float* __restrict__ dw,
                             const float* __restrict__ db, float* __restrict__ out) {
    int b = blockIdx.x * blockDim.x + threadIdx.x;
    if (b >= BB) return;
    float acc = db[0];
    for (int l = 0; l < 3; ++l)
        for (int j = 0; j < HH; ++j)
            acc += a[(l * BB + b) * HH + j] * dw[l * HH + j];
    out[b] = acc;
}

extern "C" void kernel_launch(void* const* d_in, const int* in_sizes, int n_in,
                              void* d_out, int out_size, void* d_ws, size_t ws_size,
                              hipStream_t stream) {
    (void)in_sizes; (void)n_in; (void)out_size; (void)ws_size;
    const float* x = (const float*)d_in[0];
    const float* w[3]    = {(const float*)d_in[1],  (const float*)d_in[10], (const float*)d_in[19]};
    const float* uu[3]   = {(const float*)d_in[2],  (const float*)d_in[11], (const float*)d_in[20]};
    const float* bi[3]   = {(const float*)d_in[3],  (const float*)d_in[12], (const float*)d_in[21]};
    const float* gam[3]  = {(const float*)d_in[4],  (const float*)d_in[13], (const float*)d_in[22]};
    const float* bet[3]  = {(const float*)d_in[5],  (const float*)d_in[14], (const float*)d_in[23]};
    const float* mea[3]  = {(const float*)d_in[6],  (const float*)d_in[15], (const float*)d_in[24]};
    const float* var[3]  = {(const float*)d_in[7],  (const float*)d_in[16], (const float*)d_in[25]};
    const float* atw[3]  = {(const float*)d_in[8],  (const float*)d_in[17], (const float*)d_in[26]};
    const float* atv[3]  = {(const float*)d_in[9],  (const float*)d_in[18], (const float*)d_in[27]};
    const float* dw = (const float*)d_in[28];
    const float* db = (const float*)d_in[29];

    float* ws = (float*)d_ws;
    size_t off = 0;
    // cross-layer h buffers, parity double-buffered: Hb[layer][parity]
    float* Hb[2][2];
    for (int l = 0; l < 2; ++l)
        for (int p = 0; p < 2; ++p) { Hb[l][p] = ws + off; off += (size_t)BB * TC * HH; }
    float* st_h  = ws + off; off += 3 * BB * HH;
    float* st_c  = ws + off; off += 3 * BB * HH;
    float* st_ac = ws + off; off += 3 * BB * HH;
    float* st_m  = ws + off; off += 3 * BB;
    float* st_d  = ws + off; off += 3 * BB;
    float* s_ws  = ws + off; off += 3 * HH;
    float* ab_ws = ws + off; off += 3 * HH;
    float* wv_ws = ws + off; off += 3 * HH;
    float* W2p   = ws + off; off += HH * GG;
    float* W3p   = ws + off; off += HH * GG;
    float* b2p   = ws + off; off += GG;
    float* b3p   = ws + off; off += GG;
    float* a_ws  = ws + off; off += 3 * BB * HH;

    for (int l = 0; l < 3; ++l)
        fold1_kernel<<<1, 64, 0, stream>>>(gam[l], bet[l], mea[l], var[l], atw[l], atv[l],
                                           s_ws + l * HH, ab_ws + l * HH, wv_ws + l * HH);
    fold2_kernel<<<1, 256, 0, stream>>>(w[1], bi[1], s_ws + 0 * HH, ab_ws + 0 * HH, W2p, b2p);
    fold2_kernel<<<1, 256, 0, stream>>>(w[2], bi[2], s_ws + 1 * HH, ab_ws + 1 * HH, W3p, b3p);
    init_kernel<<<(3 * BB * HH + 255) / 256, 256, 0, stream>>>(st_h, st_c, st_ac, st_m, st_d);

    const float* Wl[3] = {w[0], W2p, W3p};
    const float* bl[3] = {bi[0], b2p, b3p};

    // software pipeline: at step s, layer l processes chunk s-l
    for (int s = 0; s <= NCHUNK - 1 + 2; ++s) {
        RecFArgs ra;
        int nseg = 0;
        for (int l = 0; l < 3; ++l) {
            int cpos = s - l;
            if (cpos < 0 || cpos >= NCHUNK) continue;
            if (l == 0) {
                ra.xin[nseg] = x + (size_t)cpos * TC * FF;
                ra.sB[nseg] = (long)TT * FF;
                ra.K[nseg] = 32;
            } else {
                ra.xin[nseg] = Hb[l - 1][(s & 1) ^ 1];   // written by layer l-1 at step s-1
                ra.sB[nseg] = (long)TC * HH;
                ra.K[nseg] = 64;
            }
            ra.W[nseg] = Wl[l]; ra.U[nseg] = uu[l]; ra.bias[nseg] = bl[l];
            ra.Hout[nseg] = (l < 2) ? Hb[l][s & 1] : (float*)0;
            ra.st_h[nseg] = st_h + l * BB * HH;
            ra.st_c[nseg] = st_c + l * BB * HH;
            ra.st_acc[nseg] = st_ac + l * BB * HH;
            ra.st_m[nseg] = st_m + l * BB;
            ra.st_d[nseg] = st_d + l * BB;
            ra.wv[nseg]  = wv_ws + l * HH;
            ra.abv[nseg] = ab_ws + l * HH;
            ra.sbn[nseg] = s_ws + l * HH;
            ra.a_out[nseg] = a_ws + l * BB * HH;
            ra.last[nseg] = (cpos == NCHUNK - 1) ? 1 : 0;
            ++nseg;
        }
        if (!nseg) continue;
        rec_fused<<<nseg * BB, 256, 0, stream>>>(ra);
    }
    final_kernel<<<(BB + 255) / 256, 256, 0, stream>>>(a_ws, dw, db, (float*)d_out);
}

// Round 7
// 846.667 us; speedup vs baseline: 2.2670x; 2.2670x over previous
//
#include <hip/hip_runtime.h>
#include <math.h>

#define BB 1024
#define TT 512
#define FF 32
#define HH 64
#define GG 256   // 4H
#define TC 64
#define NCHUNK (TT/TC)   // 8
#define MB 16            // batch rows per block
#define NBLK (BB/MB)     // 64
#define HPAD 68          // h_lds row stride (16B-aligned, uniform bank spread)
#define EPSBN 1e-3f

typedef __attribute__((ext_vector_type(8))) short bf16x8;
typedef __attribute__((ext_vector_type(4))) float f32x4;
typedef __attribute__((ext_vector_type(4))) int   i32x4;

// ---------------- fold1: per-layer BN vectors + attention vector ----------------
__global__ void fold1_kernel(const float* __restrict__ gamma, const float* __restrict__ beta,
                             const float* __restrict__ mean, const float* __restrict__ var,
                             const float* __restrict__ attw, const float* __restrict__ attv,
                             float* __restrict__ s_out, float* __restrict__ ab_out,
                             float* __restrict__ wv_out) {
    int d = threadIdx.x; // 64 threads
    float s = gamma[d] * rsqrtf(var[d] + EPSBN);
    float ab = beta[d] - mean[d] * s;
    float wvr = 0.f;
    for (int e = 0; e < HH; ++e) wvr += attw[d * HH + e] * attv[e];
    s_out[d] = s;
    ab_out[d] = ab;
    wv_out[d] = s * wvr;
}

// ---------------- fold2: fold previous layer's BN into next W, b ----------------
__global__ void fold2_kernel(const float* __restrict__ W, const float* __restrict__ b,
                             const float* __restrict__ s_prev, const float* __restrict__ ab_prev,
                             float* __restrict__ Wp, float* __restrict__ bp) {
    int g = threadIdx.x; // 256 threads
    float bacc = b[g];
    for (int d = 0; d < HH; ++d) {
        float w = W[d * GG + g];
        bacc += ab_prev[d] * w;
        Wp[d * GG + g] = s_prev[d] * w;
    }
    bp[g] = bacc;
}

// ---------------- init per-call state ----------------
__global__ void init_kernel(float* st_h, float* st_c, float* st_acc, float* st_m, float* st_d) {
    int i = blockIdx.x * blockDim.x + threadIdx.x;
    int n = 3 * BB * HH;
    if (i < n) { st_h[i] = 0.f; st_c[i] = 0.f; st_acc[i] = 0.f; }
    if (i < 3 * BB) { st_m[i] = -3.0e38f; st_d[i] = 0.f; }
}

// ---------------- helpers ----------------
__device__ __forceinline__ f32x4 ld4(const float* p) { return *reinterpret_cast<const f32x4*>(p); }
__device__ __forceinline__ void st4(float* p, f32x4 v) { *reinterpret_cast<f32x4*>(p) = v; }
__device__ __forceinline__ int cvtpk(float a, float b) {
    int r; asm("v_cvt_pk_bf16_f32 %0, %1, %2" : "=v"(r) : "v"(a), "v"(b)); return r;
}
// split 8 fp32 (k-order) into hi/lo bf16x8 fragments (hi RNE; lo = residual)
__device__ __forceinline__ void mkfrag(f32x4 A, f32x4 B, bf16x8& hi, bf16x8& lo) {
    i32x4 H, L;
    H[0] = cvtpk(A[0], A[1]); H[1] = cvtpk(A[2], A[3]);
    H[2] = cvtpk(B[0], B[1]); H[3] = cvtpk(B[2], B[3]);
    L[0] = cvtpk(A[0] - __int_as_float(H[0] << 16), A[1] - __int_as_float(H[0] & 0xffff0000));
    L[1] = cvtpk(A[2] - __int_as_float(H[1] << 16), A[3] - __int_as_float(H[1] & 0xffff0000));
    L[2] = cvtpk(B[0] - __int_as_float(H[2] << 16), B[1] - __int_as_float(H[2] & 0xffff0000));
    L[3] = cvtpk(B[2] - __int_as_float(H[3] << 16), B[3] - __int_as_float(H[3] & 0xffff0000));
    hi = __builtin_bit_cast(bf16x8, H); lo = __builtin_bit_cast(bf16x8, L);
}
__device__ __forceinline__ float sigm(float x) { return __fdividef(1.f, 1.f + __expf(-x)); }
#define MFMA(a, b, c) c = __builtin_amdgcn_mfma_f32_16x16x32_bf16(a, b, c, 0, 0, 0)

// ---------------- MFMA recurrent kernel ----------------
// Block = 16 batch rows, 4 waves. z^T = U^T.h^T + W^T.x^T: M=gate-cols(256), N=rows(16), K=units.
// Wave w owns M-tiles {w, w+4, w+8, w+12} -> lane (r=l&15 row, q=l>>4) holds ALL 4 gates for
// cells (row r, units 16w+4q+i) -> in-lane c/h update, no gate exchange. Weights = static
// A-fragments in VGPRs (hi/lo split). h feedback via [2][16][HPAD] LDS, 1 barrier/step.
// x-projection MFMAs pre-accumulated into next step's C (no h-dependency). Online attention,
// lagged one step (scores h_{t-1}); the last h is scored by the next chunk / final epilogue.
struct RecFArgs {
    const float* xin[3]; long sB[3]; long sT[3]; int K[3];
    const float* W[3]; const float* U[3]; const float* bias[3];
    float* Hout[3];              // nullptr -> skip
    float* st_h[3]; float* st_c[3]; float* st_acc[3];
    float* st_m[3]; float* st_d[3];
    const float* wv[3]; const float* abv[3]; const float* sbn[3];
    float* a_out[3];
    int last[3]; int first[3];
};

template<int KT>   // x K-tiles: 1 (K=32, layer1) or 2 (K=64)
__device__ __forceinline__ void rec_body(const RecFArgs& A, const int seg, const int b0,
                                         float (*hl)[MB][HPAD]) {
    const int tid = threadIdx.x;
    const int w = tid >> 6;
    const int l = tid & 63;
    const int r = l & 15;
    const int q = l >> 4;
    const int cw = w << 4;

    // ---- preload weights as A-fragments: A[m=gate][k=unit] = M[k][64g+cw+r], k=32kk+8q+e ----
    bf16x8 UHf[4][2], ULf[4][2], WHf[4][KT], WLf[4][KT];
    {
        const float* Up = A.U[seg];
#pragma unroll
        for (int g = 0; g < 4; ++g)
#pragma unroll
            for (int kk = 0; kk < 2; ++kk) {
                const float* p = Up + (size_t)(32 * kk + 8 * q) * GG + 64 * g + cw + r;
                f32x4 a, b;
                a[0] = p[0];      a[1] = p[GG];     a[2] = p[2 * GG]; a[3] = p[3 * GG];
                b[0] = p[4 * GG]; b[1] = p[5 * GG]; b[2] = p[6 * GG]; b[3] = p[7 * GG];
                mkfrag(a, b, UHf[g][kk], ULf[g][kk]);
            }
        const float* Wp = A.W[seg];
#pragma unroll
        for (int g = 0; g < 4; ++g)
#pragma unroll
            for (int kk = 0; kk < KT; ++kk) {
                const float* p = Wp + (size_t)(32 * kk + 8 * q) * GG + 64 * g + cw + r;
                f32x4 a, b;
                a[0] = p[0];      a[1] = p[GG];     a[2] = p[2 * GG]; a[3] = p[3 * GG];
                b[0] = p[4 * GG]; b[1] = p[5 * GG]; b[2] = p[6 * GG]; b[3] = p[7 * GG];
                mkfrag(a, b, WHf[g][kk], WLf[g][kk]);
            }
    }
    f32x4 bias4[4];
#pragma unroll
    for (int g = 0; g < 4; ++g) bias4[g] = ld4(A.bias[seg] + 64 * g + cw + 4 * q);

    f32x4 wva = ld4(A.wv[seg] + 8 * q);
    f32x4 wvb = ld4(A.wv[seg] + 8 * q + 4);
    f32x4 wvc = ld4(A.wv[seg] + 32 + 8 * q);
    f32x4 wvd = ld4(A.wv[seg] + 32 + 8 * q + 4);

    const int grow = b0 + r;
    f32x4 c4   = ld4(A.st_c[seg]   + (size_t)grow * HH + cw + 4 * q);
    f32x4 h4   = ld4(A.st_h[seg]   + (size_t)grow * HH + cw + 4 * q);
    f32x4 acc4 = ld4(A.st_acc[seg] + (size_t)grow * HH + cw + 4 * q);
    float m_b = A.st_m[seg][grow];
    float d_b = A.st_d[seg][grow];

    st4(&hl[0][r][cw + 4 * q], h4);     // waves cover disjoint unit slices -> full h

    const float* xbase = A.xin[seg] + (size_t)grow * A.sB[seg];
    const long sT = A.sT[seg];

    f32x4 XA[2 * KT], XB[2 * KT];
    auto xload = [&](f32x4 (&X)[2 * KT], int t) {
        const float* xp = xbase + (size_t)t * sT + 8 * q;
        X[0] = ld4(xp); X[1] = ld4(xp + 4);
        if constexpr (KT == 2) { X[2] = ld4(xp + 32); X[3] = ld4(xp + 32 + 4); }
    };
    xload(XA, 0);
    xload(XB, 1);

    f32x4 Ca[4], Cb[4];
    auto seedC = [&](f32x4 (&C)[4], f32x4 (&X)[2 * KT]) {
        bf16x8 xh0, xl0, xh1, xl1;
        mkfrag(X[0], X[1], xh0, xl0);
        if constexpr (KT == 2) mkfrag(X[2], X[3], xh1, xl1);
#pragma unroll
        for (int g = 0; g < 4; ++g) {
            C[g] = bias4[g];
            MFMA(WHf[g][0], xh0, C[g]);
            MFMA(WHf[g][0], xl0, C[g]);
            MFMA(WLf[g][0], xh0, C[g]);
            if constexpr (KT == 2) {
                MFMA(WHf[g][1], xh1, C[g]);
                MFMA(WHf[g][1], xl1, C[g]);
                MFMA(WLf[g][1], xh1, C[g]);
            }
        }
    };

    auto attup = [&](int pr) {   // online softmax with h_{t-1} (in hl[pr] + cells h4)
        f32x4 f0 = ld4(&hl[pr][r][8 * q]);
        f32x4 f1 = ld4(&hl[pr][r][8 * q + 4]);
        f32x4 f2 = ld4(&hl[pr][r][32 + 8 * q]);
        f32x4 f3 = ld4(&hl[pr][r][32 + 8 * q + 4]);
        float sc = 0.f;
#pragma unroll
        for (int i = 0; i < 4; ++i) {
            sc = fmaf(f0[i], wva[i], sc);
            sc = fmaf(f1[i], wvb[i], sc);
            sc = fmaf(f2[i], wvc[i], sc);
            sc = fmaf(f3[i], wvd[i], sc);
        }
        sc += __shfl_xor(sc, 16);
        sc += __shfl_xor(sc, 32);
        float mn = fmaxf(m_b, sc);
        float corr = __expf(m_b - mn);
        float p = __expf(sc - mn);
        d_b = d_b * corr + p;
        acc4 = acc4 * corr + p * h4;
        m_b = mn;
    };

    float* Hob = A.Hout[seg];
    auto step = [&](int t, f32x4 (&C)[4], int pr, bool do_att) {
        if (Hob && w == 3 && t > 0) {    // stage h_{t-1} out (coalesced via LDS)
            const int sr = l >> 2, scol = (l & 3) << 4;
            f32x4 v0 = ld4(&hl[pr][sr][scol]);
            f32x4 v1 = ld4(&hl[pr][sr][scol + 4]);
            f32x4 v2 = ld4(&hl[pr][sr][scol + 8]);
            f32x4 v3 = ld4(&hl[pr][sr][scol + 12]);
            float* op = Hob + (size_t)(b0 + sr) * (TC * HH) + (size_t)(t - 1) * HH + scol;
            st4(op, v0); st4(op + 4, v1); st4(op + 8, v2); st4(op + 12, v3);
        }
        if (do_att) attup(pr);
        f32x4 f0 = ld4(&hl[pr][r][8 * q]);
        f32x4 f1 = ld4(&hl[pr][r][8 * q + 4]);
        f32x4 f2 = ld4(&hl[pr][r][32 + 8 * q]);
        f32x4 f3 = ld4(&hl[pr][r][32 + 8 * q + 4]);
        bf16x8 bh0, bl0, bh1, bl1;
        mkfrag(f0, f1, bh0, bl0);
        mkfrag(f2, f3, bh1, bl1);
#pragma unroll
        for (int g = 0; g < 4; ++g) {
            MFMA(UHf[g][0], bh0, C[g]);
            MFMA(UHf[g][0], bl0, C[g]);
            MFMA(ULf[g][0], bh0, C[g]);
            MFMA(UHf[g][1], bh1, C[g]);
            MFMA(UHf[g][1], bl1, C[g]);
            MFMA(ULf[g][1], bh1, C[g]);
        }
#pragma unroll
        for (int i = 0; i < 4; ++i) {
            float zi = sigm(C[0][i]);
            float zf = sigm(C[1][i]);
            float zg = fmaxf(C[2][i], 0.f);
            float zo = sigm(C[3][i]);
            c4[i] = fmaf(zf, c4[i], zi * zg);
            h4[i] = zo * fmaxf(c4[i], 0.f);
        }
        st4(&hl[pr ^ 1][r][cw + 4 * q], h4);
    };

    const bool first = (A.first[seg] != 0);
    seedC(Ca, XA);                 // z_x for t=0
    __syncthreads();               // hl[0] ready

#pragma unroll 1
    for (int it = 0; it < TC / 2; ++it) {
        const int t0 = 2 * it, t1 = 2 * it + 1;
        step(t0, Ca, 0, !(first && t0 == 0));
        xload(XA, (t0 + 2 < TC) ? t0 + 2 : TC - 1);
        seedC(Cb, XB);             // z_x for t1
        __syncthreads();
        step(t1, Cb, 1, true);
        xload(XB, (t1 + 2 < TC) ? t1 + 2 : TC - 1);
        seedC(Ca, XA);             // z_x for t0+2
        __syncthreads();
    }

    // epilogue: stage h_{TC-1}; last chunk scores it and emits attention output
    if (Hob && w == 3) {
        const int sr = l >> 2, scol = (l & 3) << 4;
        f32x4 v0 = ld4(&hl[0][sr][scol]);
        f32x4 v1 = ld4(&hl[0][sr][scol + 4]);
        f32x4 v2 = ld4(&hl[0][sr][scol + 8]);
        f32x4 v3 = ld4(&hl[0][sr][scol + 12]);
        float* op = Hob + (size_t)(b0 + sr) * (TC * HH) + (size_t)(TC - 1) * HH + scol;
        st4(op, v0); st4(op + 4, v1); st4(op + 8, v2); st4(op + 12, v3);
    }
    if (A.last[seg]) {
        attup(0);
        f32x4 sb = ld4(A.sbn[seg] + cw + 4 * q);
        f32x4 ab = ld4(A.abv[seg] + cw + 4 * q);
        f32x4 res;
#pragma unroll
        for (int i = 0; i < 4; ++i)
            res[i] = sb[i] * __fdividef(acc4[i], d_b) + ab[i];
        st4(A.a_out[seg] + (size_t)grow * HH + cw + 4 * q, res);
    }
    st4(A.st_c[seg]   + (size_t)grow * HH + cw + 4 * q, c4);
    st4(A.st_h[seg]   + (size_t)grow * HH + cw + 4 * q, h4);
    st4(A.st_acc[seg] + (size_t)grow * HH + cw + 4 * q, acc4);
    if (w == 0 && q == 0) { A.st_m[seg][grow] = m_b; A.st_d[seg][grow] = d_b; }
}

__global__ __launch_bounds__(256, 1) void rec_mfma(RecFArgs A) {
    __shared__ float hl[2][MB][HPAD];   // 8.7 KB
    const int seg = blockIdx.x >> 6;             // NBLK = 64
    const int b0 = (blockIdx.x & (NBLK - 1)) << 4;
    if (A.K[seg] == 32) rec_body<1>(A, seg, b0, hl);
    else                rec_body<2>(A, seg, b0, hl);
}

// ---------------- final: out[b] = db + sum_{l,j} a[l][b][j]*dw[l*64+j] ----------------
__global__ void final_kernel(const float* __restrict__ a, const float* __restrict__ dw,
                             const float* __restrict__ db, float* __restrict__ out) {
    int b = blockIdx.x * blockDim.x + threadIdx.x;
    if (b >= BB) return;
    float acc = db[0];
    for (int l = 0; l < 3; ++l)
        for (int j = 0; j < HH; ++j)
            acc += a[(l * BB + b) * HH + j] * dw[l * HH + j];
    out[b] = acc;
}

extern "C" void kernel_launch(void* const* d_in, const int* in_sizes, int n_in,
                              void* d_out, int out_size, void* d_ws, size_t ws_size,
                              hipStream_t stream) {
    (void)in_sizes; (void)n_in; (void)out_size; (void)ws_size;
    const float* x = (const float*)d_in[0];
    const float* w[3]    = {(const float*)d_in[1],  (const float*)d_in[10], (const float*)d_in[19]};
    const float* uu[3]   = {(const float*)d_in[2],  (const float*)d_in[11], (const float*)d_in[20]};
    const float* bi[3]   = {(const float*)d_in[3],  (const float*)d_in[12], (const float*)d_in[21]};
    const float* gam[3]  = {(const float*)d_in[4],  (const float*)d_in[13], (const float*)d_in[22]};
    const float* bet[3]  = {(const float*)d_in[5],  (const float*)d_in[14], (const float*)d_in[23]};
    const float* mea[3]  = {(const float*)d_in[6],  (const float*)d_in[15], (const float*)d_in[24]};
    const float* var[3]  = {(const float*)d_in[7],  (const float*)d_in[16], (const float*)d_in[25]};
    const float* atw[3]  = {(const float*)d_in[8],  (const float*)d_in[17], (const float*)d_in[26]};
    const float* atv[3]  = {(const float*)d_in[9],  (const float*)d_in[18], (const float*)d_in[27]};
    const float* dw = (const float*)d_in[28];
    const float* db = (const float*)d_in[29];

    float* ws = (float*)d_ws;
    size_t off = 0;
    // cross-layer h buffers, parity double-buffered: Hb[layer][parity], [BB][TC][HH]
    float* Hb[2][2];
    for (int l = 0; l < 2; ++l)
        for (int p = 0; p < 2; ++p) { Hb[l][p] = ws + off; off += (size_t)BB * TC * HH; }
    float* st_h  = ws + off; off += 3 * BB * HH;
    float* st_c  = ws + off; off += 3 * BB * HH;
    float* st_ac = ws + off; off += 3 * BB * HH;
    float* st_m  = ws + off; off += 3 * BB;
    float* st_d  = ws + off; off += 3 * BB;
    float* s_ws  = ws + off; off += 3 * HH;
    float* ab_ws = ws + off; off += 3 * HH;
    float* wv_ws = ws + off; off += 3 * HH;
    float* W2p   = ws + off; off += HH * GG;
    float* W3p   = ws + off; off += HH * GG;
    float* b2p   = ws + off; off += GG;
    float* b3p   = ws + off; off += GG;
    float* a_ws  = ws + off; off += 3 * BB * HH;

    for (int l = 0; l < 3; ++l)
        fold1_kernel<<<1, 64, 0, stream>>>(gam[l], bet[l], mea[l], var[l], atw[l], atv[l],
                                           s_ws + l * HH, ab_ws + l * HH, wv_ws + l * HH);
    fold2_kernel<<<1, 256, 0, stream>>>(w[1], bi[1], s_ws + 0 * HH, ab_ws + 0 * HH, W2p, b2p);
    fold2_kernel<<<1, 256, 0, stream>>>(w[2], bi[2], s_ws + 1 * HH, ab_ws + 1 * HH, W3p, b3p);
    init_kernel<<<(3 * BB * HH + 255) / 256, 256, 0, stream>>>(st_h, st_c, st_ac, st_m, st_d);

    const float* Wl[3] = {w[0], W2p, W3p};
    const float* bl[3] = {bi[0], b2p, b3p};

    // software pipeline: at step s, layer l processes chunk s-l
    for (int s = 0; s <= NCHUNK - 1 + 2; ++s) {
        RecFArgs ra;
        int nseg = 0;
        for (int l = 0; l < 3; ++l) {
            int cpos = s - l;
            if (cpos < 0 || cpos >= NCHUNK) continue;
            if (l == 0) {
                ra.xin[nseg] = x + (size_t)cpos * TC * FF;
                ra.sB[nseg] = (long)TT * FF;
                ra.sT[nseg] = FF;
                ra.K[nseg] = 32;
            } else {
                ra.xin[nseg] = Hb[l - 1][(s & 1) ^ 1];   // written by layer l-1 at step s-1
                ra.sB[nseg] = (long)TC * HH;
                ra.sT[nseg] = HH;
                ra.K[nseg] = 64;
            }
            ra.W[nseg] = Wl[l]; ra.U[nseg] = uu[l]; ra.bias[nseg] = bl[l];
            ra.Hout[nseg] = (l < 2) ? Hb[l][s & 1] : (float*)0;
            ra.st_h[nseg] = st_h + l * BB * HH;
            ra.st_c[nseg] = st_c + l * BB * HH;
            ra.st_acc[nseg] = st_ac + l * BB * HH;
            ra.st_m[nseg] = st_m + l * BB;
            ra.st_d[nseg] = st_d + l * BB;
            ra.wv[nseg]  = wv_ws + l * HH;
            ra.abv[nseg] = ab_ws + l * HH;
            ra.sbn[nseg] = s_ws + l * HH;
            ra.a_out[nseg] = a_ws + l * BB * HH;
            ra.last[nseg]  = (cpos == NCHUNK - 1) ? 1 : 0;
            ra.first[nseg] = (cpos == 0) ? 1 : 0;
            ++nseg;
        }
        if (!nseg) continue;
        rec_mfma<<<nseg * NBLK, 256, 0, stream>>>(ra);
    }
    final_kernel<<<(BB + 255) / 256, 256, 0, stream>>>(a_ws, dw, db, (float*)d_out);
}